// Round 1
// baseline (44.029 us; speedup 1.0000x reference)
//
#include <hip/hip_runtime.h>
#include <math.h>

#define NF 64
#define NC 16
#define LEN 2048
#define BATCH 256
#define BETA 2.5f
#define KAPPA 10.0f
#define EPSN 1e-12f

#define TPB 1024
#define NQ (TPB / NF)      // 16 q-groups
#define CHUNK (LEN / NQ)   // 128 t's per thread

__device__ __forceinline__ float clip01(float v) { return fminf(fmaxf(v, 0.0f), 1.0f); }

// ---------------------------------------------------------------------------
// Kernel A: precompute lwT[t*NF + f] = log(sig(B*(t-t1c))*sig(B*(t2c-t)) + eps)
// ---------------------------------------------------------------------------
__global__ void lw_kernel(const float* __restrict__ t1, const float* __restrict__ t2,
                          float* __restrict__ lwT) {
    int idx = blockIdx.x * blockDim.x + threadIdx.x;   // idx = t*NF + f
    if (idx >= NF * LEN) return;
    int f = idx & (NF - 1);
    int t = idx >> 6;
    float t1c = fminf(fmaxf(t1[f], 0.0f), (float)(LEN - 1));
    float t2c = fminf(fmaxf(t2[f], 0.0f), (float)(LEN - 1));
    t1c = fminf(t1c, t2c - 1.0f);
    float u = BETA * ((float)t - t1c);
    float v = BETA * (t2c - (float)t);
    float su = 1.0f / (1.0f + __expf(-u));
    float sv = 1.0f / (1.0f + __expf(-v));
    lwT[idx] = __logf(su * sv + EPSN);
}

// ---------------------------------------------------------------------------
// Kernel B: one block per batch element. Stage1 (temporal softmax-select over
// L) with 16 q-chunks per feature, then stage2 (NC over NF) and stage3 (over NC).
// ---------------------------------------------------------------------------
template <bool USE_WS>
__global__ __launch_bounds__(TPB) void main_kernel(
    const float* __restrict__ x, const float* __restrict__ av,
    const float* __restrict__ bv, const float* __restrict__ lwT,
    const float* __restrict__ t1g, const float* __restrict__ t2g,
    const float* __restrict__ p1, const float* __restrict__ p2,
    const float* __restrict__ tvt_, const float* __restrict__ tvl1_,
    const float* __restrict__ tvl2_, float* __restrict__ out) {
    __shared__ float xs[LEN * 2];        // 16 KB: x[b] row
    __shared__ float redA[NQ][NF];
    __shared__ float redB[NQ][NF];
    __shared__ float redC[NQ][NF];
    __shared__ float redD[NQ][NF];
    __shared__ float lp[NC][NF];
    __shared__ float r1s[NF];
    __shared__ float r2s[NC];

    const int b = blockIdx.x;
    const int tid = threadIdx.x;
    const int f = tid & (NF - 1);
    const int q = tid >> 6;

    // stage x[b] (4096 floats) into LDS: 1 float4 per thread
    const float4* xg = (const float4*)(x + (size_t)b * (LEN * 2));
    ((float4*)xs)[tid] = xg[tid];

    const float a = av[f];
    const float bb = bv[f];
    const int ch = f & 1;

    float t1c = 0.f, t2c = 0.f;
    if (!USE_WS) {
        t1c = fminf(fmaxf(t1g[f], 0.0f), (float)(LEN - 1));
        t2c = fminf(fmaxf(t2g[f], 0.0f), (float)(LEN - 1));
        t1c = fminf(t1c, t2c - 1.0f);
    }

    __syncthreads();

    const int t0 = q * CHUNK;

    // ---- pass 1: row maxes of z+ = B*rp+lw and z- = -B*rp+lw --------------
    float mp = -INFINITY, mm = -INFINITY;
#pragma unroll 8
    for (int k = 0; k < CHUNK; ++k) {
        int t = t0 + k;
        float lw;
        if (USE_WS) {
            lw = lwT[t * NF + f];
        } else {
            float su = 1.0f / (1.0f + __expf(-BETA * ((float)t - t1c)));
            float sv = 1.0f / (1.0f + __expf(-BETA * (t2c - (float)t)));
            lw = __logf(su * sv + EPSN);
        }
        float xv = xs[2 * t + ch];
        float rp = fmaf(a, xv, -bb);
        mp = fmaxf(mp, fmaf(BETA, rp, lw));
        mm = fmaxf(mm, fmaf(-BETA, rp, lw));
    }
    redA[q][f] = mp;
    redB[q][f] = mm;
    __syncthreads();
    float Mp = -INFINITY, Mm = -INFINITY;
#pragma unroll
    for (int j = 0; j < NQ; ++j) {
        Mp = fmaxf(Mp, redA[j][f]);
        Mm = fmaxf(Mm, redB[j][f]);
    }
    __syncthreads();   // everyone done reading redA/redB before reuse

    // ---- pass 2: exp-sums and weighted sums -------------------------------
    float sp = 0.f, wp = 0.f, sm = 0.f, wm = 0.f;
#pragma unroll 4
    for (int k = 0; k < CHUNK; ++k) {
        int t = t0 + k;
        float lw;
        if (USE_WS) {
            lw = lwT[t * NF + f];
        } else {
            float su = 1.0f / (1.0f + __expf(-BETA * ((float)t - t1c)));
            float sv = 1.0f / (1.0f + __expf(-BETA * (t2c - (float)t)));
            lw = __logf(su * sv + EPSN);
        }
        float xv = xs[2 * t + ch];
        float rp = fmaf(a, xv, -bb);
        float ep = __expf(fmaf(BETA, rp, lw) - Mp);
        float em = __expf(fmaf(-BETA, rp, lw) - Mm);
        sp += ep;
        wp = fmaf(ep, rp, wp);
        sm += em;
        wm = fmaf(em, rp, wm);
    }
    redA[q][f] = sp;
    redB[q][f] = wp;
    redC[q][f] = sm;
    redD[q][f] = wm;

    // fill log(p1) table while we're at it (1024 entries, 1 per thread)
    {
        float pv = clip01(p1[tid]);
        ((float*)lp)[tid] = __logf(pv + EPSN);
    }
    __syncthreads();

    // ---- combine q-partials -> r1[f] --------------------------------------
    if (q == 0) {
        float Sp = 0.f, Wp = 0.f, Sm = 0.f, Wm = 0.f;
#pragma unroll
        for (int j = 0; j < NQ; ++j) {
            Sp += redA[j][f];
            Wp += redB[j][f];
            Sm += redC[j][f];
            Wm += redD[j][f];
        }
        float rmax = Wp / Sp;
        float rmin = Wm / Sm;
        float tvt = clip01(tvt_[f]);
        r1s[f] = tvt * rmax + (1.0f - tvt) * rmin;
    }
    __syncthreads();

    // ---- stage 2: per clause c, softmax-select over NF --------------------
    if (tid < NC) {
        const int c = tid;
        float mo = -INFINITY, ma = -INFINITY;
#pragma unroll
        for (int ff = 0; ff < NF; ++ff) {
            float z = KAPPA * r1s[ff];
            float l = lp[c][ff];
            mo = fmaxf(mo, z + l);
            ma = fmaxf(ma, l - z);
        }
        float so = 0.f, wo = 0.f, sa = 0.f, wa = 0.f;
#pragma unroll
        for (int ff = 0; ff < NF; ++ff) {
            float r1v = r1s[ff];
            float z = KAPPA * r1v;
            float l = lp[c][ff];
            float eo = __expf(z + l - mo);
            float ea = __expf(l - z - ma);
            so += eo;
            wo = fmaf(eo, r1v, wo);
            sa += ea;
            wa = fmaf(ea, r1v, wa);
        }
        float tvl1 = clip01(tvl1_[c]);
        r2s[c] = tvl1 * (wo / so) + (1.0f - tvl1) * (wa / sa);
    }
    __syncthreads();

    // ---- stage 3: softmax-select over NC, write r[b] ----------------------
    if (tid == 0) {
        float mo = -INFINITY, ma = -INFINITY;
#pragma unroll
        for (int c = 0; c < NC; ++c) {
            float l = __logf(clip01(p2[c]) + EPSN);
            float z = KAPPA * r2s[c];
            mo = fmaxf(mo, z + l);
            ma = fmaxf(ma, l - z);
        }
        float so = 0.f, wo = 0.f, sa = 0.f, wa = 0.f;
#pragma unroll
        for (int c = 0; c < NC; ++c) {
            float l = __logf(clip01(p2[c]) + EPSN);
            float r2v = r2s[c];
            float z = KAPPA * r2v;
            float eo = __expf(z + l - mo);
            float ea = __expf(l - z - ma);
            so += eo;
            wo = fmaf(eo, r2v, wo);
            sa += ea;
            wa = fmaf(ea, r2v, wa);
        }
        float tvl2 = clip01(tvl2_[0]);
        out[b] = tvl2 * (wo / so) + (1.0f - tvl2) * (wa / sa);
    }
}

// ---------------------------------------------------------------------------
// Kernel C: reg scalar
// ---------------------------------------------------------------------------
__global__ void reg_kernel(const float* __restrict__ p1, const float* __restrict__ p2,
                           const float* __restrict__ tvt, const float* __restrict__ tvl1,
                           const float* __restrict__ tvl2, float* __restrict__ out) {
    __shared__ float red[256];
    int tid = threadIdx.x;
    float acc = 0.0f;
    for (int i = tid; i < NC * NF; i += 256) {
        float p = clip01(p1[i]);
        acc += 0.01f * (p * (1.0f - p)) + 0.01f * (p * p);
    }
    if (tid < NC) {
        float p = clip01(p2[tid]);
        acc += 0.01f * (p * (1.0f - p)) + 0.01f * (p * p);
    }
    if (tid < NF) {
        float c = clip01(tvt[tid]);
        acc += 0.01f * (c * (1.0f - c));
    }
    if (tid < NC) {
        float c = clip01(tvl1[tid]);
        acc += 0.01f * (c * (1.0f - c));
    }
    if (tid == 0) {
        float c = clip01(tvl2[0]);
        acc += 0.01f * (c * (1.0f - c));
    }
    red[tid] = acc;
    __syncthreads();
    for (int s = 128; s > 0; s >>= 1) {
        if (tid < s) red[tid] += red[tid + s];
        __syncthreads();
    }
    if (tid == 0) out[BATCH] = red[0];
}

// ---------------------------------------------------------------------------
extern "C" void kernel_launch(void* const* d_in, const int* in_sizes, int n_in,
                              void* d_out, int out_size, void* d_ws, size_t ws_size,
                              hipStream_t stream) {
    const float* x    = (const float*)d_in[0];
    const float* t1   = (const float*)d_in[1];
    const float* t2   = (const float*)d_in[2];
    const float* a    = (const float*)d_in[3];
    const float* bv   = (const float*)d_in[4];
    const float* p1   = (const float*)d_in[5];
    const float* p2   = (const float*)d_in[6];
    const float* tvt  = (const float*)d_in[7];
    const float* tvl1 = (const float*)d_in[8];
    const float* tvl2 = (const float*)d_in[9];
    float* out = (float*)d_out;
    float* lwT = (float*)d_ws;

    const bool use_ws = (d_ws != nullptr) && (ws_size >= (size_t)(NF * LEN) * sizeof(float));

    if (use_ws) {
        lw_kernel<<<(NF * LEN + 255) / 256, 256, 0, stream>>>(t1, t2, lwT);
        main_kernel<true><<<BATCH, TPB, 0, stream>>>(x, a, bv, lwT, t1, t2, p1, p2,
                                                     tvt, tvl1, tvl2, out);
    } else {
        main_kernel<false><<<BATCH, TPB, 0, stream>>>(x, a, bv, nullptr, t1, t2, p1, p2,
                                                      tvt, tvl1, tvl2, out);
    }
    reg_kernel<<<1, 256, 0, stream>>>(p1, p2, tvt, tvl1, tvl2, out);
}

// Round 2
// 28.530 us; speedup vs baseline: 1.5432x; 1.5432x over previous
//
#include <hip/hip_runtime.h>
#include <math.h>

#define NF 64
#define NC 16
#define LEN 2048
#define BATCH 256
#define BETA 2.5f
#define KAPPA 10.0f
#define EPSN 1e-12f
#define LOG2E 1.4426950408889634f

#define SPLIT 2
#define HALF (LEN / SPLIT)          // 1024 t's per block
#define TPB 1024
#define NQ (TPB / NF)               // 16 q-groups
#define CHUNK (HALF / NQ)           // 64 t's per thread (split path)
#define CHUNK_MONO (LEN / NQ)       // 128 t's per thread (mono path)

__device__ __forceinline__ float clip01(float v) { return fminf(fmaxf(v, 0.0f), 1.0f); }

__device__ __forceinline__ float fexp2(float x) {
#if __has_builtin(__builtin_amdgcn_exp2f)
    return __builtin_amdgcn_exp2f(x);
#else
    return exp2f(x);
#endif
}

// ---------------------------------------------------------------------------
// Kernel A: lwT[t*NF+f] = log2(sig(B*(t-t1c))*sig(B*(t2c-t)) + eps)
// (log2 domain so the main loop uses native v_exp_f32 without the ln2 mul)
// ---------------------------------------------------------------------------
__global__ void lw_kernel(const float* __restrict__ t1, const float* __restrict__ t2,
                          float* __restrict__ lwT) {
    int idx = blockIdx.x * blockDim.x + threadIdx.x;   // idx = t*NF + f
    if (idx >= NF * LEN) return;
    int f = idx & (NF - 1);
    int t = idx >> 6;
    float t1c = fminf(fmaxf(t1[f], 0.0f), (float)(LEN - 1));
    float t2c = fminf(fmaxf(t2[f], 0.0f), (float)(LEN - 1));
    t1c = fminf(t1c, t2c - 1.0f);
    float su = 1.0f / (1.0f + __expf(-BETA * ((float)t - t1c)));
    float sv = 1.0f / (1.0f + __expf(-BETA * (t2c - (float)t)));
    lwT[idx] = __log2f(su * sv + EPSN);
}

// ---------------------------------------------------------------------------
// Kernel B (split path): grid = BATCH*SPLIT, block = 1024. Single-pass
// (no max subtraction) exp2 accumulation; per-(b,f,half) quadruple -> ws.
// ---------------------------------------------------------------------------
__global__ __launch_bounds__(TPB) void main_split(
    const float* __restrict__ x, const float* __restrict__ av,
    const float* __restrict__ bv, const float* __restrict__ lwT,
    float4* __restrict__ part) {
    __shared__ float xs[HALF * 2];         // 8 KB
    __shared__ float4 redQ[NQ][NF];        // 16 KB

    const int b = blockIdx.x >> 1;
    const int h = blockIdx.x & 1;
    const int tid = threadIdx.x;
    const int f = tid & (NF - 1);
    const int q = tid >> 6;

    // stage this half of x[b]: 2048 floats, one float2 per thread
    ((float2*)xs)[tid] = ((const float2*)(x + (size_t)b * (LEN * 2) + h * (HALF * 2)))[tid];

    const float a = av[f];
    const float bb = bv[f];
    const int ch = f & 1;
    const float B2 = BETA * LOG2E;

    __syncthreads();

    const int lt0 = q * CHUNK;
    const int gt0 = h * HALF + lt0;

    float sp = 0.f, wp = 0.f, sm = 0.f, wm = 0.f;
#pragma unroll 8
    for (int k = 0; k < CHUNK; ++k) {
        float lw2 = lwT[(gt0 + k) * NF + f];
        float xv = xs[2 * (lt0 + k) + ch];
        float rp = fmaf(a, xv, -bb);
        float ep = fexp2(fmaf(B2, rp, lw2));
        float em = fexp2(fmaf(-B2, rp, lw2));
        sp += ep;
        wp = fmaf(ep, rp, wp);
        sm += em;
        wm = fmaf(em, rp, wm);
    }
    redQ[q][f] = make_float4(sp, wp, sm, wm);
    __syncthreads();

    if (q == 0) {
        float Sp = 0.f, Wp = 0.f, Sm = 0.f, Wm = 0.f;
#pragma unroll
        for (int j = 0; j < NQ; ++j) {
            float4 v = redQ[j][f];
            Sp += v.x; Wp += v.y; Sm += v.z; Wm += v.w;
        }
        part[(size_t)h * BATCH * NF + (size_t)b * NF + f] = make_float4(Sp, Wp, Sm, Wm);
    }
}

// ---------------------------------------------------------------------------
// Kernel C (split path): combine halves -> r1[f], then stages 2+3.
// grid = BATCH, block = 64.
// ---------------------------------------------------------------------------
__global__ __launch_bounds__(64) void finish_kernel(
    const float4* __restrict__ part, const float* __restrict__ p1,
    const float* __restrict__ p2, const float* __restrict__ tvt_,
    const float* __restrict__ tvl1_, const float* __restrict__ tvl2_,
    float* __restrict__ out) {
    __shared__ float r1s[NF];
    __shared__ float lp[NC][NF];
    __shared__ float r2s[NC];

    const int b = blockIdx.x;
    const int f = threadIdx.x;
    const float KL = KAPPA * LOG2E;

    float4 A = part[(size_t)b * NF + f];
    float4 Bq = part[(size_t)BATCH * NF + (size_t)b * NF + f];
    float Sp = A.x + Bq.x, Wp = A.y + Bq.y, Sm = A.z + Bq.z, Wm = A.w + Bq.w;
    float tvt = clip01(tvt_[f]);
    r1s[f] = tvt * (Wp / Sp) + (1.0f - tvt) * (Wm / Sm);

#pragma unroll
    for (int c = 0; c < NC; ++c)
        lp[c][f] = __log2f(clip01(p1[c * NF + f]) + EPSN);
    __syncthreads();

    if (f < NC) {
        const int c = f;
        float mo = -INFINITY, ma = -INFINITY;
#pragma unroll
        for (int ff = 0; ff < NF; ++ff) {
            float z = KL * r1s[ff];
            float l = lp[c][ff];
            mo = fmaxf(mo, z + l);
            ma = fmaxf(ma, l - z);
        }
        float so = 0.f, wo = 0.f, sa = 0.f, wa = 0.f;
#pragma unroll
        for (int ff = 0; ff < NF; ++ff) {
            float r1v = r1s[ff];
            float z = KL * r1v;
            float l = lp[c][ff];
            float eo = fexp2(z + l - mo);
            float ea = fexp2(l - z - ma);
            so += eo; wo = fmaf(eo, r1v, wo);
            sa += ea; wa = fmaf(ea, r1v, wa);
        }
        float tvl1 = clip01(tvl1_[c]);
        r2s[c] = tvl1 * (wo / so) + (1.0f - tvl1) * (wa / sa);
    }
    __syncthreads();

    if (f == 0) {
        float mo = -INFINITY, ma = -INFINITY;
#pragma unroll
        for (int c = 0; c < NC; ++c) {
            float l = __log2f(clip01(p2[c]) + EPSN);
            float z = KL * r2s[c];
            mo = fmaxf(mo, z + l);
            ma = fmaxf(ma, l - z);
        }
        float so = 0.f, wo = 0.f, sa = 0.f, wa = 0.f;
#pragma unroll
        for (int c = 0; c < NC; ++c) {
            float l = __log2f(clip01(p2[c]) + EPSN);
            float r2v = r2s[c];
            float z = KL * r2v;
            float eo = fexp2(z + l - mo);
            float ea = fexp2(l - z - ma);
            so += eo; wo = fmaf(eo, r2v, wo);
            sa += ea; wa = fmaf(ea, r2v, wa);
        }
        float tvl2 = clip01(tvl2_[0]);
        out[b] = tvl2 * (wo / so) + (1.0f - tvl2) * (wa / sa);
    }
}

// ---------------------------------------------------------------------------
// Fallback (mono) kernel: whole pipeline per block, single pass. Used only
// when ws is too small for the split path.
// ---------------------------------------------------------------------------
template <bool USE_WS>
__global__ __launch_bounds__(TPB) void main_mono(
    const float* __restrict__ x, const float* __restrict__ av,
    const float* __restrict__ bv, const float* __restrict__ lwT,
    const float* __restrict__ t1g, const float* __restrict__ t2g,
    const float* __restrict__ p1, const float* __restrict__ p2,
    const float* __restrict__ tvt_, const float* __restrict__ tvl1_,
    const float* __restrict__ tvl2_, float* __restrict__ out) {
    __shared__ float xs[LEN * 2];
    __shared__ float4 redQ[NQ][NF];
    __shared__ float lp[NC][NF];
    __shared__ float r1s[NF];
    __shared__ float r2s[NC];

    const int b = blockIdx.x;
    const int tid = threadIdx.x;
    const int f = tid & (NF - 1);
    const int q = tid >> 6;
    const float B2 = BETA * LOG2E;
    const float KL = KAPPA * LOG2E;

    ((float4*)xs)[tid] = ((const float4*)(x + (size_t)b * (LEN * 2)))[tid];

    const float a = av[f];
    const float bb = bv[f];
    const int ch = f & 1;

    float t1c = 0.f, t2c = 0.f;
    if (!USE_WS) {
        t1c = fminf(fmaxf(t1g[f], 0.0f), (float)(LEN - 1));
        t2c = fminf(fmaxf(t2g[f], 0.0f), (float)(LEN - 1));
        t1c = fminf(t1c, t2c - 1.0f);
    }
    __syncthreads();

    const int t0 = q * CHUNK_MONO;
    float sp = 0.f, wp = 0.f, sm = 0.f, wm = 0.f;
#pragma unroll 8
    for (int k = 0; k < CHUNK_MONO; ++k) {
        int t = t0 + k;
        float lw2;
        if (USE_WS) {
            lw2 = lwT[t * NF + f];
        } else {
            float su = 1.0f / (1.0f + __expf(-BETA * ((float)t - t1c)));
            float sv = 1.0f / (1.0f + __expf(-BETA * (t2c - (float)t)));
            lw2 = __log2f(su * sv + EPSN);
        }
        float xv = xs[2 * t + ch];
        float rp = fmaf(a, xv, -bb);
        float ep = fexp2(fmaf(B2, rp, lw2));
        float em = fexp2(fmaf(-B2, rp, lw2));
        sp += ep; wp = fmaf(ep, rp, wp);
        sm += em; wm = fmaf(em, rp, wm);
    }
    redQ[q][f] = make_float4(sp, wp, sm, wm);
    {
        float pv = clip01(p1[tid]);
        ((float*)lp)[tid] = __log2f(pv + EPSN);
    }
    __syncthreads();

    if (q == 0) {
        float Sp = 0.f, Wp = 0.f, Sm = 0.f, Wm = 0.f;
#pragma unroll
        for (int j = 0; j < NQ; ++j) {
            float4 v = redQ[j][f];
            Sp += v.x; Wp += v.y; Sm += v.z; Wm += v.w;
        }
        float tvt = clip01(tvt_[f]);
        r1s[f] = tvt * (Wp / Sp) + (1.0f - tvt) * (Wm / Sm);
    }
    __syncthreads();

    if (tid < NC) {
        const int c = tid;
        float mo = -INFINITY, ma = -INFINITY;
#pragma unroll
        for (int ff = 0; ff < NF; ++ff) {
            float z = KL * r1s[ff];
            float l = lp[c][ff];
            mo = fmaxf(mo, z + l);
            ma = fmaxf(ma, l - z);
        }
        float so = 0.f, wo = 0.f, sa = 0.f, wa = 0.f;
#pragma unroll
        for (int ff = 0; ff < NF; ++ff) {
            float r1v = r1s[ff];
            float z = KL * r1v;
            float l = lp[c][ff];
            float eo = fexp2(z + l - mo);
            float ea = fexp2(l - z - ma);
            so += eo; wo = fmaf(eo, r1v, wo);
            sa += ea; wa = fmaf(ea, r1v, wa);
        }
        float tvl1 = clip01(tvl1_[c]);
        r2s[c] = tvl1 * (wo / so) + (1.0f - tvl1) * (wa / sa);
    }
    __syncthreads();

    if (tid == 0) {
        float mo = -INFINITY, ma = -INFINITY;
#pragma unroll
        for (int c = 0; c < NC; ++c) {
            float l = __log2f(clip01(p2[c]) + EPSN);
            float z = KL * r2s[c];
            mo = fmaxf(mo, z + l);
            ma = fmaxf(ma, l - z);
        }
        float so = 0.f, wo = 0.f, sa = 0.f, wa = 0.f;
#pragma unroll
        for (int c = 0; c < NC; ++c) {
            float l = __log2f(clip01(p2[c]) + EPSN);
            float r2v = r2s[c];
            float z = KL * r2v;
            float eo = fexp2(z + l - mo);
            float ea = fexp2(l - z - ma);
            so += eo; wo = fmaf(eo, r2v, wo);
            sa += ea; wa = fmaf(ea, r2v, wa);
        }
        float tvl2 = clip01(tvl2_[0]);
        out[b] = tvl2 * (wo / so) + (1.0f - tvl2) * (wa / sa);
    }
}

// ---------------------------------------------------------------------------
// Kernel D: reg scalar -> out[BATCH]
// ---------------------------------------------------------------------------
__global__ void reg_kernel(const float* __restrict__ p1, const float* __restrict__ p2,
                           const float* __restrict__ tvt, const float* __restrict__ tvl1,
                           const float* __restrict__ tvl2, float* __restrict__ out) {
    __shared__ float red[256];
    int tid = threadIdx.x;
    float acc = 0.0f;
    for (int i = tid; i < NC * NF; i += 256) {
        float p = clip01(p1[i]);
        acc += 0.01f * (p * (1.0f - p)) + 0.01f * (p * p);
    }
    if (tid < NC) {
        float p = clip01(p2[tid]);
        acc += 0.01f * (p * (1.0f - p)) + 0.01f * (p * p);
    }
    if (tid < NF) {
        float c = clip01(tvt[tid]);
        acc += 0.01f * (c * (1.0f - c));
    }
    if (tid < NC) {
        float c = clip01(tvl1[tid]);
        acc += 0.01f * (c * (1.0f - c));
    }
    if (tid == 0) {
        float c = clip01(tvl2[0]);
        acc += 0.01f * (c * (1.0f - c));
    }
    red[tid] = acc;
    __syncthreads();
    for (int s = 128; s > 0; s >>= 1) {
        if (tid < s) red[tid] += red[tid + s];
        __syncthreads();
    }
    if (tid == 0) out[BATCH] = red[0];
}

// ---------------------------------------------------------------------------
extern "C" void kernel_launch(void* const* d_in, const int* in_sizes, int n_in,
                              void* d_out, int out_size, void* d_ws, size_t ws_size,
                              hipStream_t stream) {
    const float* x    = (const float*)d_in[0];
    const float* t1   = (const float*)d_in[1];
    const float* t2   = (const float*)d_in[2];
    const float* a    = (const float*)d_in[3];
    const float* bv   = (const float*)d_in[4];
    const float* p1   = (const float*)d_in[5];
    const float* p2   = (const float*)d_in[6];
    const float* tvt  = (const float*)d_in[7];
    const float* tvl1 = (const float*)d_in[8];
    const float* tvl2 = (const float*)d_in[9];
    float* out = (float*)d_out;

    const size_t lw_bytes = (size_t)(NF * LEN) * sizeof(float);                 // 512 KB
    const size_t part_bytes = (size_t)SPLIT * BATCH * NF * sizeof(float4);      // 512 KB

    if (d_ws && ws_size >= lw_bytes + part_bytes) {
        float* lwT = (float*)d_ws;
        float4* part = (float4*)((char*)d_ws + lw_bytes);
        lw_kernel<<<(NF * LEN + 255) / 256, 256, 0, stream>>>(t1, t2, lwT);
        main_split<<<BATCH * SPLIT, TPB, 0, stream>>>(x, a, bv, lwT, part);
        finish_kernel<<<BATCH, 64, 0, stream>>>(part, p1, p2, tvt, tvl1, tvl2, out);
    } else if (d_ws && ws_size >= lw_bytes) {
        float* lwT = (float*)d_ws;
        lw_kernel<<<(NF * LEN + 255) / 256, 256, 0, stream>>>(t1, t2, lwT);
        main_mono<true><<<BATCH, TPB, 0, stream>>>(x, a, bv, lwT, t1, t2, p1, p2,
                                                   tvt, tvl1, tvl2, out);
    } else {
        main_mono<false><<<BATCH, TPB, 0, stream>>>(x, a, bv, nullptr, t1, t2, p1, p2,
                                                    tvt, tvl1, tvl2, out);
    }
    reg_kernel<<<1, 256, 0, stream>>>(p1, p2, tvt, tvl1, tvl2, out);
}